// Round 8
// baseline (1709.698 us; speedup 1.0000x reference)
//
#include <hip/hip_runtime.h>
#include <math.h>

#define NN 100000
#define EE 800000
#define DH 128
#define NL 16
#define GEMM_GRID 1563
#define S1_GRID 3125     // 32 nodes/block * 3125 = 100000 exactly
#define NSLOT 32

typedef __bf16 bf16x8 __attribute__((ext_vector_type(8)));
typedef float f32x4 __attribute__((ext_vector_type(4)));

// ---------------- CSR build ----------------
__global__ void k_hist(const int* __restrict__ row, int* __restrict__ cnt) {
    int e = blockIdx.x * 256 + threadIdx.x;
    if (e < EE) atomicAdd(&cnt[row[e]], 1);
}

__global__ void k_scan1(const int* __restrict__ cnt, int* __restrict__ rp, int* __restrict__ part) {
    __shared__ int buf[512];
    int tid = threadIdx.x;
    int i = blockIdx.x * 512 + tid;
    int v = (i < NN) ? cnt[i] : 0;
    buf[tid] = v;
    __syncthreads();
    for (int off = 1; off < 512; off <<= 1) {
        int x = (tid >= off) ? buf[tid - off] : 0;
        __syncthreads();
        buf[tid] += x;
        __syncthreads();
    }
    if (i < NN) rp[i] = buf[tid] - v;
    if (tid == 511) part[blockIdx.x] = buf[511];
}

__global__ void k_scan2(int* __restrict__ part, int nparts) {
    __shared__ int buf[256];
    int tid = threadIdx.x;
    int v = (tid < nparts) ? part[tid] : 0;
    buf[tid] = v;
    __syncthreads();
    for (int off = 1; off < 256; off <<= 1) {
        int x = (tid >= off) ? buf[tid - off] : 0;
        __syncthreads();
        buf[tid] += x;
        __syncthreads();
    }
    if (tid < nparts) part[tid] = buf[tid] - v;
}

__global__ void k_scan3(int* __restrict__ rp, const int* __restrict__ part) {
    int i = blockIdx.x * 512 + threadIdx.x;
    if (i < NN) rp[i] += part[blockIdx.x];
    if (i == 0) rp[NN] = EE;
}

// w prescaled by (1-ALPHA)=0.9 so the gather loop is a pure fma chain
__global__ void k_fill(const int* __restrict__ row, const int* __restrict__ col,
                       const float* __restrict__ w, const int* __restrict__ rp,
                       int* __restrict__ fil, int2* __restrict__ ep) {
    int e = blockIdx.x * 256 + threadIdx.x;
    if (e >= EE) return;
    int r = row[e];
    int pos = rp[r] + atomicAdd(&fil[r], 1);
    ep[pos] = make_int2(col[e], __float_as_int(0.9f * w[e]));
}

// ---------------- weight prep: split hi/lo bf16 + swizzle to MFMA fragment order ----------------
// frag[t][ks][lane][e] = M[k][j], j = t*16 + (lane&15), k = ks*32 + (lane>>4)*8 + e
__global__ void k_prep_w(const float* __restrict__ convW, const float* __restrict__ Win,
                         __bf16* __restrict__ Bhi, __bf16* __restrict__ Blo) {
    int l = blockIdx.x;
    const float* W;
    float beta, ob;
    if (l < NL) {
        beta = logf(0.5f / (float)(l + 1) + 1.0f);
        ob = 1.0f - beta;
        W = convW + (size_t)l * DH * DH;
    } else {
        beta = 1.0f;
        ob = 0.0f;
        W = Win;
    }
    __bf16* bh = Bhi + (size_t)l * DH * DH;
    __bf16* bl = Blo + (size_t)l * DH * DH;
    for (int i = threadIdx.x; i < DH * DH; i += 256) {
        int k = i >> 7, j = i & 127;
        float v = beta * W[i] + ((k == j) ? ob : 0.f);
        __bf16 hv = (__bf16)v;
        int t = j >> 4, n = j & 15, ks = k >> 5, quad = (k >> 3) & 3, e = k & 7;
        int off = ((t * 4 + ks) * 64 + quad * 16 + n) * 8 + e;
        bh[off] = hv;
        bl[off] = (__bf16)(v - (float)hv);
    }
}

__global__ void k_prep_out(const float* __restrict__ Wout, __bf16* __restrict__ Bhi, __bf16* __restrict__ Blo) {
    for (int i = threadIdx.x; i < DH * 48; i += 256) {
        int k = i / 48, j = i % 48;
        float v = (j < 40) ? Wout[k * 40 + j] : 0.f;
        __bf16 hv = (__bf16)v;
        int t = j >> 4, n = j & 15, ks = k >> 5, quad = (k >> 3) & 3, e = k & 7;
        int off = ((t * 4 + ks) * 64 + quad * 16 + n) * 8 + e;
        Bhi[off] = hv;
        Blo[off] = (__bf16)(v - (float)hv);
    }
}

__device__ inline void split8(const float* p, bf16x8& hi, bf16x8& lo) {
    f32x4 v0 = *(const f32x4*)p;
    f32x4 v1 = *(const f32x4*)(p + 4);
#pragma unroll
    for (int j = 0; j < 4; ++j) {
        __bf16 h0 = (__bf16)v0[j];
        hi[j] = h0;
        lo[j] = (__bf16)(v0[j] - (float)h0);
        __bf16 h1 = (__bf16)v1[j];
        hi[4 + j] = h1;
        lo[4 + j] = (__bf16)(v1[j] - (float)h1);
    }
}

#define MFMA(a, b, c) __builtin_amdgcn_mfma_f32_16x16x32_bf16(a, b, c, 0, 0, 0)

// ---------------- S1: spmm+mix -> a (global + LDS), then MFMA stats of a' = a@M ----------------
// Gather: 8 nodes/wave, 8 independent chains, 16 lanes... (8 lanes/node, 16 feats = 2x16B loads/lane).
// Stats: per-block a'(32 rows) via MFMA (B frags direct from global), column sum/sumsq -> 32-slot atomics.
__global__ __launch_bounds__(256) void k_spmm_stats(const __bf16* __restrict__ h, const __bf16* __restrict__ x0,
                                                    const int* __restrict__ rp, const int2* __restrict__ ep,
                                                    const __bf16* __restrict__ Bhi, const __bf16* __restrict__ Blo,
                                                    __bf16* __restrict__ a, float* __restrict__ stats32) {
    __shared__ __bf16 aS[32 * 136];   // row stride 136 -> conflict-free patterns (verified R6)
    __shared__ float red[2][2][DH];   // [rt][sum/sumsq][feature]
    int tid = threadIdx.x;
    int wave = tid >> 6, lane = tid & 63;

    // ---- gather phase ----
    int c = lane >> 3;        // chain 0..7
    int sl = lane & 7;        // lane within chain
    int fo = sl * 16;         // 16 features per lane
    int nl = wave * 8 + c;    // local row 0..31
    int node = blockIdx.x * 32 + nl;  // exact cover of [0,100000)

    bf16x8 xa = *(const bf16x8*)&x0[(size_t)node * DH + fo];
    bf16x8 xb = *(const bf16x8*)&x0[(size_t)node * DH + fo + 8];
    float acc[16];
#pragma unroll
    for (int i = 0; i < 8; ++i) {
        acc[i] = 0.1f * (float)xa[i];
        acc[8 + i] = 0.1f * (float)xb[i];
    }
    int s = rp[node], e = rp[node + 1];
    int j = s;
    for (; j + 1 < e; j += 2) {
        int2 p0 = ep[j], p1 = ep[j + 1];
        const __bf16* h0 = &h[(size_t)p0.x * DH + fo];
        const __bf16* h1 = &h[(size_t)p1.x * DH + fo];
        bf16x8 v0a = *(const bf16x8*)h0, v0b = *(const bf16x8*)(h0 + 8);
        bf16x8 v1a = *(const bf16x8*)h1, v1b = *(const bf16x8*)(h1 + 8);
        float w0 = __int_as_float(p0.y), w1 = __int_as_float(p1.y);
#pragma unroll
        for (int i = 0; i < 8; ++i) {
            acc[i] = fmaf(w0, (float)v0a[i], acc[i]);
            acc[8 + i] = fmaf(w0, (float)v0b[i], acc[8 + i]);
            acc[i] = fmaf(w1, (float)v1a[i], acc[i]);
            acc[8 + i] = fmaf(w1, (float)v1b[i], acc[8 + i]);
        }
    }
    if (j < e) {
        int2 p = ep[j];
        const __bf16* hp = &h[(size_t)p.x * DH + fo];
        bf16x8 va = *(const bf16x8*)hp, vb = *(const bf16x8*)(hp + 8);
        float w = __int_as_float(p.y);
#pragma unroll
        for (int i = 0; i < 8; ++i) {
            acc[i] = fmaf(w, (float)va[i], acc[i]);
            acc[8 + i] = fmaf(w, (float)vb[i], acc[8 + i]);
        }
    }
    bf16x8 oa, ob;
#pragma unroll
    for (int i = 0; i < 8; ++i) {
        oa[i] = (__bf16)acc[i];
        ob[i] = (__bf16)acc[8 + i];
    }
    *(bf16x8*)&a[(size_t)node * DH + fo] = oa;
    *(bf16x8*)&a[(size_t)node * DH + fo + 8] = ob;
    *(bf16x8*)&aS[nl * 136 + fo] = oa;
    *(bf16x8*)&aS[nl * 136 + fo + 8] = ob;
    __syncthreads();

    // ---- MFMA stats phase: a' = aS @ M, column sum/sumsq over the block's 32 rows ----
    int n = lane & 15, quad = lane >> 4;
    int rt = wave & 1;            // row tile 0..1 (16 rows each)
    int t0 = (wave >> 1) * 4;     // 4 col tiles per wave
#pragma unroll
    for (int tt = 0; tt < 4; ++tt) {
        int t = t0 + tt;
        f32x4 acc4 = (f32x4){0.f, 0.f, 0.f, 0.f};
#pragma unroll
        for (int ks = 0; ks < 4; ++ks) {
            bf16x8 av = *(const bf16x8*)&aS[(rt * 16 + n) * 136 + ks * 32 + quad * 8];
            int base = ((t * 4 + ks) * 64 + lane) * 8;
            bf16x8 bh = *(const bf16x8*)&Bhi[base];
            bf16x8 bl = *(const bf16x8*)&Blo[base];
            acc4 = MFMA(av, bh, acc4);
            acc4 = MFMA(av, bl, acc4);
        }
        float sv = 0.f, qv = 0.f;
#pragma unroll
        for (int r = 0; r < 4; ++r) {
            float v = acc4[r];
            sv += v;
            qv += v * v;
        }
        sv += __shfl_xor(sv, 16); sv += __shfl_xor(sv, 32);
        qv += __shfl_xor(qv, 16); qv += __shfl_xor(qv, 32);
        if (quad == 0) {
            red[rt][0][t * 16 + n] = sv;
            red[rt][1][t * 16 + n] = qv;
        }
    }
    __syncthreads();
    {
        int which = tid >> 7, jj = tid & 127;
        float tot = red[0][which][jj] + red[1][which][jj];
        atomicAdd(&stats32[(size_t)(blockIdx.x & (NSLOT - 1)) * 256 + tid], tot);  // ~98 adds/addr
    }
}

// ---------------- G2: a' = a@M recomputed, fused BN + residual + relu -> h ----------------
__global__ __launch_bounds__(256) void k_gemm_bn(const __bf16* __restrict__ A, const __bf16* __restrict__ hin,
                                                 __bf16* __restrict__ hout,
                                                 const __bf16* __restrict__ Bhi, const __bf16* __restrict__ Blo,
                                                 const float* __restrict__ stats32,
                                                 const float* __restrict__ gamma, const float* __restrict__ bbeta) {
    __shared__ __bf16 Bs[2 * DH * DH];
    __shared__ float sums[256];
    __shared__ float scb[DH], shb[DH];
    int tid = threadIdx.x;
    {
        const f32x4* sh = (const f32x4*)Bhi;
        const f32x4* sl = (const f32x4*)Blo;
        f32x4* dh = (f32x4*)Bs;
        f32x4* dl = (f32x4*)(Bs + DH * DH);
#pragma unroll
        for (int i = 0; i < 8; ++i) {
            dh[tid + i * 256] = sh[tid + i * 256];
            dl[tid + i * 256] = sl[tid + i * 256];
        }
    }
    {
        float ss = 0.f;
#pragma unroll
        for (int s = 0; s < NSLOT; ++s) ss += stats32[(size_t)s * 256 + tid];
        sums[tid] = ss;
    }
    __syncthreads();
    if (tid < DH) {
        float s = sums[tid], q = sums[128 + tid];
        float mu = s * (1.0f / NN);
        float var = q * (1.0f / NN) - mu * mu;
        if (var < 0.f) var = 0.f;
        float sc = gamma[tid] * rsqrtf(var + 1e-5f);
        scb[tid] = sc;
        shb[tid] = bbeta[tid] - mu * sc;
    }
    __syncthreads();

    int wave = tid >> 6, lane = tid & 63;
    int n = lane & 15, quad = lane >> 4;
    int r0 = blockIdx.x * 64 + wave * 16;
    int arow = r0 + n;
    if (arow > NN - 1) arow = NN - 1;
    const __bf16* pa = A + (size_t)arow * DH + quad * 8;

    f32x4 acc[8];
#pragma unroll
    for (int t = 0; t < 8; ++t) acc[t] = (f32x4){0.f, 0.f, 0.f, 0.f};

#pragma unroll
    for (int ks = 0; ks < 4; ++ks) {
        bf16x8 av = *(const bf16x8*)(pa + ks * 32);
#pragma unroll
        for (int t = 0; t < 8; ++t) {
            int base = ((t * 4 + ks) * 64 + lane) * 8;
            bf16x8 bh = *(const bf16x8*)&Bs[base];
            bf16x8 bl = *(const bf16x8*)&Bs[DH * DH + base];
            acc[t] = MFMA(av, bh, acc[t]);
            acc[t] = MFMA(av, bl, acc[t]);
        }
    }

#pragma unroll
    for (int t = 0; t < 8; ++t) {
        float sc = scb[t * 16 + n];
        float sh = shb[t * 16 + n];
#pragma unroll
        for (int r = 0; r < 4; ++r) {
            int row = r0 + quad * 4 + r;
            if (row < NN) {
                size_t idx = (size_t)row * DH + t * 16 + n;
                float hv = (float)hin[idx];
                float v = fmaxf(fmaf(acc[t][r], sc, sh) + hv, 0.f);
                hout[idx] = (__bf16)v;
            }
        }
    }
}

// ---------------- input GEMM: x0 = relu(X @ Win + bin), fp32 A split on the fly, B in LDS ----------------
__global__ __launch_bounds__(256) void k_lin_in(const float* __restrict__ X,
                                                const __bf16* __restrict__ Bhi, const __bf16* __restrict__ Blo,
                                                const float* __restrict__ bin, __bf16* __restrict__ x0) {
    __shared__ __bf16 Bs[2 * DH * DH];
    int tid = threadIdx.x;
    {
        const f32x4* sh = (const f32x4*)Bhi;
        const f32x4* sl = (const f32x4*)Blo;
        f32x4* dh = (f32x4*)Bs;
        f32x4* dl = (f32x4*)(Bs + DH * DH);
#pragma unroll
        for (int i = 0; i < 8; ++i) {
            dh[tid + i * 256] = sh[tid + i * 256];
            dl[tid + i * 256] = sl[tid + i * 256];
        }
    }
    __syncthreads();

    int wave = tid >> 6, lane = tid & 63;
    int n = lane & 15, quad = lane >> 4;
    int r0 = blockIdx.x * 64 + wave * 16;
    int arow = r0 + n;
    if (arow > NN - 1) arow = NN - 1;
    const float* pa = X + (size_t)arow * DH + quad * 8;

    f32x4 acc[8];
#pragma unroll
    for (int t = 0; t < 8; ++t) acc[t] = (f32x4){0.f, 0.f, 0.f, 0.f};

#pragma unroll
    for (int ks = 0; ks < 4; ++ks) {
        bf16x8 ah, al;
        split8(pa + ks * 32, ah, al);
#pragma unroll
        for (int t = 0; t < 8; ++t) {
            int base = ((t * 4 + ks) * 64 + lane) * 8;
            bf16x8 bh = *(const bf16x8*)&Bs[base];
            bf16x8 bl = *(const bf16x8*)&Bs[DH * DH + base];
            acc[t] = MFMA(ah, bh, acc[t]);
            acc[t] = MFMA(al, bh, acc[t]);
            acc[t] = MFMA(ah, bl, acc[t]);
        }
    }

#pragma unroll
    for (int t = 0; t < 8; ++t) {
        float bj = bin[t * 16 + n];
#pragma unroll
        for (int r = 0; r < 4; ++r) {
            int row = r0 + quad * 4 + r;
            if (row < NN) {
                float v = fmaxf(acc[t][r] + bj, 0.f);
                x0[(size_t)row * DH + t * 16 + n] = (__bf16)v;
            }
        }
    }
}

// ---------------- output GEMM: out = h @ Wout + bout (3 tiles of 16 cols), B in LDS ----------------
__global__ __launch_bounds__(256) void k_gemm_out(const __bf16* __restrict__ A,
                                                  const __bf16* __restrict__ Bhi, const __bf16* __restrict__ Blo,
                                                  const float* __restrict__ bout, float* __restrict__ out) {
    __shared__ __bf16 Bs[2 * 48 * DH];
    int tid = threadIdx.x;
    {
        const f32x4* sh = (const f32x4*)Bhi;
        const f32x4* sl = (const f32x4*)Blo;
        f32x4* dh = (f32x4*)Bs;
        f32x4* dl = (f32x4*)(Bs + 48 * DH);
#pragma unroll
        for (int i = 0; i < 3; ++i) {
            dh[tid + i * 256] = sh[tid + i * 256];
            dl[tid + i * 256] = sl[tid + i * 256];
        }
    }
    __syncthreads();

    int wave = tid >> 6, lane = tid & 63;
    int n = lane & 15, quad = lane >> 4;
    int r0 = blockIdx.x * 64 + wave * 16;
    int arow = r0 + n;
    if (arow > NN - 1) arow = NN - 1;
    const __bf16* pa = A + (size_t)arow * DH + quad * 8;

    f32x4 acc[3];
#pragma unroll
    for (int t = 0; t < 3; ++t) acc[t] = (f32x4){0.f, 0.f, 0.f, 0.f};

#pragma unroll
    for (int ks = 0; ks < 4; ++ks) {
        bf16x8 av = *(const bf16x8*)(pa + ks * 32);
#pragma unroll
        for (int t = 0; t < 3; ++t) {
            int base = ((t * 4 + ks) * 64 + lane) * 8;
            bf16x8 bh = *(const bf16x8*)&Bs[base];
            bf16x8 bl = *(const bf16x8*)&Bs[48 * DH + base];
            acc[t] = MFMA(av, bh, acc[t]);
            acc[t] = MFMA(av, bl, acc[t]);
        }
    }

#pragma unroll
    for (int t = 0; t < 3; ++t) {
        int j = t * 16 + n;
        float bj = (j < 40) ? bout[j] : 0.f;
#pragma unroll
        for (int r = 0; r < 4; ++r) {
            int row = r0 + quad * 4 + r;
            if (row < NN && j < 40) out[(size_t)row * 40 + j] = acc[t][r] + bj;
        }
    }
}

extern "C" void kernel_launch(void* const* d_in, const int* in_sizes, int n_in,
                              void* d_out, int out_size, void* d_ws, size_t ws_size,
                              hipStream_t stream) {
    const float* x = (const float*)d_in[0];
    const float* ew = (const float*)d_in[1];
    const float* Win = (const float*)d_in[2];
    const float* bin = (const float*)d_in[3];
    const float* convW = (const float*)d_in[4];
    const float* gamma = (const float*)d_in[5];
    const float* bbeta = (const float*)d_in[6];
    const float* Wout = (const float*)d_in[7];
    const float* bout = (const float*)d_in[8];
    const int* erow = (const int*)d_in[9];
    const int* ecol = (const int*)d_in[10];
    float* out = (float*)d_out;

    char* wsp = (char*)d_ws;
    size_t off = 0;
    auto alloc = [&](size_t bytes) -> void* {
        void* p = wsp + off;
        off += (bytes + 255) & ~(size_t)255;
        return p;
    };
    __bf16* x0 = (__bf16*)alloc((size_t)NN * DH * 2);
    __bf16* h = (__bf16*)alloc((size_t)NN * DH * 2);
    __bf16* a = (__bf16*)alloc((size_t)NN * DH * 2);
    int* rp = (int*)alloc((NN + 1) * 4);
    // zero-init region: cnt | fil | stats32 as ONE memset
    size_t zero_bytes = (size_t)NN * 4 + (size_t)NN * 4 + (size_t)NL * NSLOT * 256 * 4;
    int* cnt = (int*)alloc(zero_bytes);
    int* fil = cnt + NN;
    float* stats32 = (float*)(fil + NN);
    int2* ep = (int2*)alloc((size_t)EE * 8);
    int* part = (int*)alloc(256 * 4);
    __bf16* Bhi = (__bf16*)alloc((size_t)(NL + 1) * DH * DH * 2);
    __bf16* Blo = (__bf16*)alloc((size_t)(NL + 1) * DH * DH * 2);
    __bf16* Bohi = (__bf16*)alloc((size_t)DH * 48 * 2);
    __bf16* Bolo = (__bf16*)alloc((size_t)DH * 48 * 2);

    hipMemsetAsync(cnt, 0, zero_bytes, stream);

    k_hist<<<3125, 256, 0, stream>>>(erow, cnt);
    k_scan1<<<196, 512, 0, stream>>>(cnt, rp, part);
    k_scan2<<<1, 256, 0, stream>>>(part, 196);
    k_scan3<<<196, 512, 0, stream>>>(rp, part);
    k_fill<<<3125, 256, 0, stream>>>(erow, ecol, ew, rp, fil, ep);

    k_prep_w<<<NL + 1, 256, 0, stream>>>(convW, Win, Bhi, Blo);
    k_prep_out<<<1, 256, 0, stream>>>(Wout, Bohi, Bolo);

    k_lin_in<<<GEMM_GRID, 256, 0, stream>>>(x, Bhi + (size_t)NL * DH * DH, Blo + (size_t)NL * DH * DH, bin, x0);

    for (int l = 0; l < NL; ++l) {
        const __bf16* hin = (l == 0) ? x0 : h;
        const __bf16* bh = Bhi + (size_t)l * DH * DH;
        const __bf16* bl = Blo + (size_t)l * DH * DH;
        float* st = stats32 + (size_t)l * NSLOT * 256;
        k_spmm_stats<<<S1_GRID, 256, 0, stream>>>(hin, x0, rp, ep, bh, bl, a, st);
        k_gemm_bn<<<GEMM_GRID, 256, 0, stream>>>(a, hin, h, bh, bl, st, gamma + l * DH, bbeta + l * DH);
    }
    k_gemm_out<<<GEMM_GRID, 256, 0, stream>>>(h, Bohi, Bolo, bout, out);
}

// Round 9
// 1466.090 us; speedup vs baseline: 1.1662x; 1.1662x over previous
//
#include <hip/hip_runtime.h>
#include <math.h>

#define NN 100000
#define EE 800000
#define DH 128
#define NL 16
#define GEMM_GRID 1563
#define SPMM_GRID 6250   // 16 nodes/block * 6250 = 100000 exactly
#define NSLOT 32

typedef __bf16 bf16x8 __attribute__((ext_vector_type(8)));
typedef __bf16 bf16x2 __attribute__((ext_vector_type(2)));
typedef float f32x4 __attribute__((ext_vector_type(4)));

// ---------------- CSR build ----------------
__global__ void k_hist(const int* __restrict__ row, int* __restrict__ cnt) {
    int e = blockIdx.x * 256 + threadIdx.x;
    if (e < EE) atomicAdd(&cnt[row[e]], 1);
}

__global__ void k_scan1(const int* __restrict__ cnt, int* __restrict__ rp, int* __restrict__ part) {
    __shared__ int buf[512];
    int tid = threadIdx.x;
    int i = blockIdx.x * 512 + tid;
    int v = (i < NN) ? cnt[i] : 0;
    buf[tid] = v;
    __syncthreads();
    for (int off = 1; off < 512; off <<= 1) {
        int x = (tid >= off) ? buf[tid - off] : 0;
        __syncthreads();
        buf[tid] += x;
        __syncthreads();
    }
    if (i < NN) rp[i] = buf[tid] - v;
    if (tid == 511) part[blockIdx.x] = buf[511];
}

__global__ void k_scan2(int* __restrict__ part, int nparts) {
    __shared__ int buf[256];
    int tid = threadIdx.x;
    int v = (tid < nparts) ? part[tid] : 0;
    buf[tid] = v;
    __syncthreads();
    for (int off = 1; off < 256; off <<= 1) {
        int x = (tid >= off) ? buf[tid - off] : 0;
        __syncthreads();
        buf[tid] += x;
        __syncthreads();
    }
    if (tid < nparts) part[tid] = buf[tid] - v;
}

__global__ void k_scan3(int* __restrict__ rp, const int* __restrict__ part) {
    int i = blockIdx.x * 512 + threadIdx.x;
    if (i < NN) rp[i] += part[blockIdx.x];
    if (i == 0) rp[NN] = EE;
}

// w prescaled by (1-ALPHA)=0.9 so the gather loop is a pure fma chain
__global__ void k_fill(const int* __restrict__ row, const int* __restrict__ col,
                       const float* __restrict__ w, const int* __restrict__ rp,
                       int* __restrict__ fil, int2* __restrict__ ep) {
    int e = blockIdx.x * 256 + threadIdx.x;
    if (e >= EE) return;
    int r = row[e];
    int pos = rp[r] + atomicAdd(&fil[r], 1);
    ep[pos] = make_int2(col[e], __float_as_int(0.9f * w[e]));
}

// ---------------- weight prep: split hi/lo bf16 + swizzle to MFMA fragment order ----------------
// frag[t][ks][lane][e] = M[k][j], j = t*16 + (lane&15), k = ks*32 + (lane>>4)*8 + e
__global__ void k_prep_w(const float* __restrict__ convW, const float* __restrict__ Win,
                         __bf16* __restrict__ Bhi, __bf16* __restrict__ Blo) {
    int l = blockIdx.x;
    const float* W;
    float beta, ob;
    if (l < NL) {
        beta = logf(0.5f / (float)(l + 1) + 1.0f);
        ob = 1.0f - beta;
        W = convW + (size_t)l * DH * DH;
    } else {
        beta = 1.0f;
        ob = 0.0f;
        W = Win;
    }
    __bf16* bh = Bhi + (size_t)l * DH * DH;
    __bf16* bl = Blo + (size_t)l * DH * DH;
    for (int i = threadIdx.x; i < DH * DH; i += 256) {
        int k = i >> 7, j = i & 127;
        float v = beta * W[i] + ((k == j) ? ob : 0.f);
        __bf16 hv = (__bf16)v;
        int t = j >> 4, n = j & 15, ks = k >> 5, quad = (k >> 3) & 3, e = k & 7;
        int off = ((t * 4 + ks) * 64 + quad * 16 + n) * 8 + e;
        bh[off] = hv;
        bl[off] = (__bf16)(v - (float)hv);
    }
}

__global__ void k_prep_out(const float* __restrict__ Wout, __bf16* __restrict__ Bhi, __bf16* __restrict__ Blo) {
    for (int i = threadIdx.x; i < DH * 48; i += 256) {
        int k = i / 48, j = i % 48;
        float v = (j < 40) ? Wout[k * 40 + j] : 0.f;
        __bf16 hv = (__bf16)v;
        int t = j >> 4, n = j & 15, ks = k >> 5, quad = (k >> 3) & 3, e = k & 7;
        int off = ((t * 4 + ks) * 64 + quad * 16 + n) * 8 + e;
        Bhi[off] = hv;
        Blo[off] = (__bf16)(v - (float)hv);
    }
}

// ---------------- SpMM + mix: a = (Adj@h scaled) + 0.1*x0 ----------------
// 4 node-streams per wave: 16 lanes/node, lane covers 8 feats (bf16x8 = 16B).
// Each stream gathers its node's edges independently -> 4x memory-level parallelism.
__global__ __launch_bounds__(256) void k_spmm(const __bf16* __restrict__ h, const __bf16* __restrict__ x0,
                                              const int* __restrict__ rp, const int2* __restrict__ ep,
                                              __bf16* __restrict__ a) {
    int tid = threadIdx.x;
    int wave = tid >> 6, lane = tid & 63;
    int stream = lane >> 4;          // 0..3
    int sl = lane & 15;              // lane within stream
    int fo = sl * 8;                 // feature offset (8 feats)
    int node = blockIdx.x * 16 + wave * 4 + stream;   // exact cover of [0,100000)

    bf16x8 xv = *(const bf16x8*)&x0[(size_t)node * DH + fo];
    float acc[8];
#pragma unroll
    for (int c = 0; c < 8; ++c) acc[c] = 0.1f * (float)xv[c];

    int s = rp[node], e = rp[node + 1];
    int j = s;
    for (; j + 1 < e; j += 2) {
        int2 p0 = ep[j], p1 = ep[j + 1];
        bf16x8 v0 = *(const bf16x8*)&h[(size_t)p0.x * DH + fo];
        bf16x8 v1 = *(const bf16x8*)&h[(size_t)p1.x * DH + fo];
        float w0 = __int_as_float(p0.y), w1 = __int_as_float(p1.y);
#pragma unroll
        for (int c = 0; c < 8; ++c) {
            acc[c] = fmaf(w0, (float)v0[c], acc[c]);
            acc[c] = fmaf(w1, (float)v1[c], acc[c]);
        }
    }
    if (j < e) {
        int2 p = ep[j];
        bf16x8 v = *(const bf16x8*)&h[(size_t)p.x * DH + fo];
        float w = __int_as_float(p.y);
#pragma unroll
        for (int c = 0; c < 8; ++c) acc[c] = fmaf(w, (float)v[c], acc[c]);
    }
    bf16x8 o;
#pragma unroll
    for (int c = 0; c < 8; ++c) o[c] = (__bf16)acc[c];
    *(bf16x8*)&a[(size_t)node * DH + fo] = o;
}

__device__ inline void split8(const float* p, bf16x8& hi, bf16x8& lo) {
    f32x4 v0 = *(const f32x4*)p;
    f32x4 v1 = *(const f32x4*)(p + 4);
#pragma unroll
    for (int j = 0; j < 4; ++j) {
        __bf16 h0 = (__bf16)v0[j];
        hi[j] = h0;
        lo[j] = (__bf16)(v0[j] - (float)h0);
        __bf16 h1 = (__bf16)v1[j];
        hi[4 + j] = h1;
        lo[4 + j] = (__bf16)(v1[j] - (float)h1);
    }
}

#define MFMA(a, b, c) __builtin_amdgcn_mfma_f32_16x16x32_bf16(a, b, c, 0, 0, 0)

// ---------------- layer GEMM: B fragments staged in LDS; stats -> NSLOT atomic slots ----------------
__global__ __launch_bounds__(256) void k_gemm_mfma(const __bf16* __restrict__ A, __bf16* __restrict__ Aout,
                                                   const __bf16* __restrict__ Bhi, const __bf16* __restrict__ Blo,
                                                   float* __restrict__ stats32) {
    __shared__ __bf16 Bs[2 * DH * DH];  // [hi|lo] in MFMA fragment order -> stride-1 conflict-free b128 reads
    __shared__ float red[2][4][DH];
    int tid = threadIdx.x;
    {
        const f32x4* sh = (const f32x4*)Bhi;
        const f32x4* sl = (const f32x4*)Blo;
        f32x4* dh = (f32x4*)Bs;
        f32x4* dl = (f32x4*)(Bs + DH * DH);
#pragma unroll
        for (int i = 0; i < 8; ++i) {
            dh[tid + i * 256] = sh[tid + i * 256];
            dl[tid + i * 256] = sl[tid + i * 256];
        }
    }
    __syncthreads();

    int wave = tid >> 6, lane = tid & 63;
    int n = lane & 15, quad = lane >> 4;
    int r0 = blockIdx.x * 64 + wave * 16;
    int arow = r0 + n;
    if (arow > NN - 1) arow = NN - 1;
    const __bf16* pa = A + (size_t)arow * DH + quad * 8;

    f32x4 acc[8];
#pragma unroll
    for (int t = 0; t < 8; ++t) acc[t] = (f32x4){0.f, 0.f, 0.f, 0.f};

#pragma unroll
    for (int ks = 0; ks < 4; ++ks) {
        bf16x8 av = *(const bf16x8*)(pa + ks * 32);
#pragma unroll
        for (int t = 0; t < 8; ++t) {
            int base = ((t * 4 + ks) * 64 + lane) * 8;
            bf16x8 bh = *(const bf16x8*)&Bs[base];
            bf16x8 bl = *(const bf16x8*)&Bs[DH * DH + base];
            acc[t] = MFMA(av, bh, acc[t]);
            acc[t] = MFMA(av, bl, acc[t]);
        }
    }

#pragma unroll
    for (int t = 0; t < 8; ++t) {
        float s = 0.f, q = 0.f;
#pragma unroll
        for (int r = 0; r < 4; ++r) {
            int row = r0 + quad * 4 + r;
            float v = acc[t][r];
            if (row < NN) {
                Aout[(size_t)row * DH + t * 16 + n] = (__bf16)v;
                s += v;
                q += v * v;
            }
        }
        s += __shfl_xor(s, 16); s += __shfl_xor(s, 32);
        q += __shfl_xor(q, 16); q += __shfl_xor(q, 32);
        if (quad == 0) {
            red[0][wave][t * 16 + n] = s;
            red[1][wave][t * 16 + n] = q;
        }
    }
    __syncthreads();
    {
        int which = tid >> 7, j = tid & 127;
        float tot = red[which][0][j] + red[which][1][j] + red[which][2][j] + red[which][3][j];
        // ~49 adds per address across 32 slots: contention diluted (R8-verified pattern)
        atomicAdd(&stats32[(size_t)(blockIdx.x & (NSLOT - 1)) * 256 + tid], tot);
    }
}

// ---------------- input GEMM: x0 = relu(X @ Win + bin), fp32 A split on the fly, B in LDS ----------------
__global__ __launch_bounds__(256) void k_lin_in(const float* __restrict__ X,
                                                const __bf16* __restrict__ Bhi, const __bf16* __restrict__ Blo,
                                                const float* __restrict__ bin, __bf16* __restrict__ x0) {
    __shared__ __bf16 Bs[2 * DH * DH];
    int tid = threadIdx.x;
    {
        const f32x4* sh = (const f32x4*)Bhi;
        const f32x4* sl = (const f32x4*)Blo;
        f32x4* dh = (f32x4*)Bs;
        f32x4* dl = (f32x4*)(Bs + DH * DH);
#pragma unroll
        for (int i = 0; i < 8; ++i) {
            dh[tid + i * 256] = sh[tid + i * 256];
            dl[tid + i * 256] = sl[tid + i * 256];
        }
    }
    __syncthreads();

    int wave = tid >> 6, lane = tid & 63;
    int n = lane & 15, quad = lane >> 4;
    int r0 = blockIdx.x * 64 + wave * 16;
    int arow = r0 + n;
    if (arow > NN - 1) arow = NN - 1;
    const float* pa = X + (size_t)arow * DH + quad * 8;

    f32x4 acc[8];
#pragma unroll
    for (int t = 0; t < 8; ++t) acc[t] = (f32x4){0.f, 0.f, 0.f, 0.f};

#pragma unroll
    for (int ks = 0; ks < 4; ++ks) {
        bf16x8 ah, al;
        split8(pa + ks * 32, ah, al);
#pragma unroll
        for (int t = 0; t < 8; ++t) {
            int base = ((t * 4 + ks) * 64 + lane) * 8;
            bf16x8 bh = *(const bf16x8*)&Bs[base];
            bf16x8 bl = *(const bf16x8*)&Bs[DH * DH + base];
            acc[t] = MFMA(ah, bh, acc[t]);
            acc[t] = MFMA(al, bh, acc[t]);
            acc[t] = MFMA(ah, bl, acc[t]);
        }
    }

#pragma unroll
    for (int t = 0; t < 8; ++t) {
        float bj = bin[t * 16 + n];
#pragma unroll
        for (int r = 0; r < 4; ++r) {
            int row = r0 + quad * 4 + r;
            if (row < NN) {
                float v = fmaxf(acc[t][r] + bj, 0.f);
                x0[(size_t)row * DH + t * 16 + n] = (__bf16)v;
            }
        }
    }
}

// ---------------- output GEMM: out = h @ Wout + bout (3 tiles of 16 cols), B in LDS ----------------
__global__ __launch_bounds__(256) void k_gemm_out(const __bf16* __restrict__ A,
                                                  const __bf16* __restrict__ Bhi, const __bf16* __restrict__ Blo,
                                                  const float* __restrict__ bout, float* __restrict__ out) {
    __shared__ __bf16 Bs[2 * 48 * DH];
    int tid = threadIdx.x;
    {
        const f32x4* sh = (const f32x4*)Bhi;
        const f32x4* sl = (const f32x4*)Blo;
        f32x4* dh = (f32x4*)Bs;
        f32x4* dl = (f32x4*)(Bs + 48 * DH);
#pragma unroll
        for (int i = 0; i < 3; ++i) {
            dh[tid + i * 256] = sh[tid + i * 256];
            dl[tid + i * 256] = sl[tid + i * 256];
        }
    }
    __syncthreads();

    int wave = tid >> 6, lane = tid & 63;
    int n = lane & 15, quad = lane >> 4;
    int r0 = blockIdx.x * 64 + wave * 16;
    int arow = r0 + n;
    if (arow > NN - 1) arow = NN - 1;
    const __bf16* pa = A + (size_t)arow * DH + quad * 8;

    f32x4 acc[3];
#pragma unroll
    for (int t = 0; t < 3; ++t) acc[t] = (f32x4){0.f, 0.f, 0.f, 0.f};

#pragma unroll
    for (int ks = 0; ks < 4; ++ks) {
        bf16x8 av = *(const bf16x8*)(pa + ks * 32);
#pragma unroll
        for (int t = 0; t < 3; ++t) {
            int base = ((t * 4 + ks) * 64 + lane) * 8;
            bf16x8 bh = *(const bf16x8*)&Bs[base];
            bf16x8 bl = *(const bf16x8*)&Bs[48 * DH + base];
            acc[t] = MFMA(av, bh, acc[t]);
            acc[t] = MFMA(av, bl, acc[t]);
        }
    }

#pragma unroll
    for (int t = 0; t < 3; ++t) {
        int j = t * 16 + n;
        float bj = (j < 40) ? bout[j] : 0.f;
#pragma unroll
        for (int r = 0; r < 4; ++r) {
            int row = r0 + quad * 4 + r;
            if (row < NN && j < 40) out[(size_t)row * 40 + j] = acc[t][r] + bj;
        }
    }
}

// ---------------- fused slot-reduce + BN-finalize + update: h_out = relu(a*sc + sh + h_in) ----------------
__global__ __launch_bounds__(256) void k_update(const __bf16* __restrict__ a, const __bf16* __restrict__ hin,
                                                __bf16* __restrict__ hout, const float* __restrict__ stats32,
                                                const float* __restrict__ gamma, const float* __restrict__ bbeta) {
    __shared__ float scb[DH], shb[DH];
    int tid = threadIdx.x;
    if (tid < DH) {
        float s = 0.f, q = 0.f;
#pragma unroll
        for (int sl = 0; sl < NSLOT; ++sl) {
            s += stats32[(size_t)sl * 256 + tid];
            q += stats32[(size_t)sl * 256 + 128 + tid];
        }
        float mu = s * (1.0f / NN);
        float var = q * (1.0f / NN) - mu * mu;
        if (var < 0.f) var = 0.f;
        float sc = gamma[tid] * rsqrtf(var + 1e-5f);
        scb[tid] = sc;
        shb[tid] = bbeta[tid] - mu * sc;
    }
    __syncthreads();

    int idx = blockIdx.x * 256 + tid;
    int j0 = (idx & 15) * 8;
    bf16x8 av = ((const bf16x8*)a)[idx];
    bf16x8 hv = ((const bf16x8*)hin)[idx];
    bf16x8 o;
#pragma unroll
    for (int c = 0; c < 8; ++c) {
        int j = j0 + c;
        float v = fmaxf(fmaf((float)av[c], scb[j], shb[j]) + (float)hv[c], 0.f);
        o[c] = (__bf16)v;
    }
    ((bf16x8*)hout)[idx] = o;
}

extern "C" void kernel_launch(void* const* d_in, const int* in_sizes, int n_in,
                              void* d_out, int out_size, void* d_ws, size_t ws_size,
                              hipStream_t stream) {
    const float* x = (const float*)d_in[0];
    const float* ew = (const float*)d_in[1];
    const float* Win = (const float*)d_in[2];
    const float* bin = (const float*)d_in[3];
    const float* convW = (const float*)d_in[4];
    const float* gamma = (const float*)d_in[5];
    const float* bbeta = (const float*)d_in[6];
    const float* Wout = (const float*)d_in[7];
    const float* bout = (const float*)d_in[8];
    const int* erow = (const int*)d_in[9];
    const int* ecol = (const int*)d_in[10];
    float* out = (float*)d_out;

    char* wsp = (char*)d_ws;
    size_t off = 0;
    auto alloc = [&](size_t bytes) -> void* {
        void* p = wsp + off;
        off += (bytes + 255) & ~(size_t)255;
        return p;
    };
    __bf16* x0 = (__bf16*)alloc((size_t)NN * DH * 2);
    __bf16* h = (__bf16*)alloc((size_t)NN * DH * 2);
    __bf16* a = (__bf16*)alloc((size_t)NN * DH * 2);
    int* rp = (int*)alloc((NN + 1) * 4);
    // zero-init region: cnt | fil | stats32 as ONE memset
    size_t zero_bytes = (size_t)NN * 4 + (size_t)NN * 4 + (size_t)NL * NSLOT * 256 * 4;
    int* cnt = (int*)alloc(zero_bytes);
    int* fil = cnt + NN;
    float* stats32 = (float*)(fil + NN);
    int2* ep = (int2*)alloc((size_t)EE * 8);
    int* part = (int*)alloc(256 * 4);
    __bf16* Bhi = (__bf16*)alloc((size_t)(NL + 1) * DH * DH * 2);
    __bf16* Blo = (__bf16*)alloc((size_t)(NL + 1) * DH * DH * 2);
    __bf16* Bohi = (__bf16*)alloc((size_t)DH * 48 * 2);
    __bf16* Bolo = (__bf16*)alloc((size_t)DH * 48 * 2);

    hipMemsetAsync(cnt, 0, zero_bytes, stream);

    k_hist<<<3125, 256, 0, stream>>>(erow, cnt);
    k_scan1<<<196, 512, 0, stream>>>(cnt, rp, part);
    k_scan2<<<1, 256, 0, stream>>>(part, 196);
    k_scan3<<<196, 512, 0, stream>>>(rp, part);
    k_fill<<<3125, 256, 0, stream>>>(erow, ecol, ew, rp, fil, ep);

    k_prep_w<<<NL + 1, 256, 0, stream>>>(convW, Win, Bhi, Blo);
    k_prep_out<<<1, 256, 0, stream>>>(Wout, Bohi, Bolo);

    k_lin_in<<<GEMM_GRID, 256, 0, stream>>>(x, Bhi + (size_t)NL * DH * DH, Blo + (size_t)NL * DH * DH, bin, x0);

    for (int l = 0; l < NL; ++l) {
        const __bf16* hin = (l == 0) ? x0 : h;
        float* st = stats32 + (size_t)l * NSLOT * 256;
        k_spmm<<<SPMM_GRID, 256, 0, stream>>>(hin, x0, rp, ep, a);
        k_gemm_mfma<<<GEMM_GRID, 256, 0, stream>>>(a, a, Bhi + (size_t)l * DH * DH, Blo + (size_t)l * DH * DH, st);
        k_update<<<6250, 256, 0, stream>>>(a, hin, h, st, gamma + l * DH, bbeta + l * DH);
    }
    k_gemm_out<<<GEMM_GRID, 256, 0, stream>>>(h, Bohi, Bolo, bout, out);
}